// Round 6
// baseline (164.143 us; speedup 1.0000x reference)
//
#include <hip/hip_runtime.h>
#include <math.h>

constexpr int Bn  = 8;
constexpr int Cc  = 512;
constexpr int Ss  = 1024;   // H*W
constexpr int Ee  = 512;
constexpr int nHd = 8;
constexpr int Hd  = 64;
constexpr int Gg  = 32;
constexpr int Cpg = 16;

typedef __bf16 bf16x8 __attribute__((ext_vector_type(8)));
typedef float  f32x4  __attribute__((ext_vector_type(4)));
typedef float  f32x16 __attribute__((ext_vector_type(16)));
typedef unsigned u32x4 __attribute__((ext_vector_type(4)));

__device__ inline __bf16 cvt_bf16(float f) {
    unsigned u = __builtin_bit_cast(unsigned, f);
    u += 0x7fffu + ((u >> 16) & 1u);          // RTNE (finite values)
    unsigned short h = (unsigned short)(u >> 16);
    return __builtin_bit_cast(__bf16, h);
}

__device__ inline void gld16(const __bf16* g, __bf16* l) {
    __builtin_amdgcn_global_load_lds(
        (const __attribute__((address_space(1))) void*)g,
        (__attribute__((address_space(3))) void*)l, 16, 0, 0);
}

// pack two fp32 -> 2 bf16 (RTZ) in one dword: low = lo, high = hi
__device__ inline unsigned pk_bf16_rtz(float hi, float lo) {
    return __builtin_amdgcn_perm(__builtin_bit_cast(unsigned, hi),
                                 __builtin_bit_cast(unsigned, lo), 0x07060302u);
}

// ---------------------------------------------------------------------------
// Pre-pass: fused transposes (+ zero the GroupNorm stats buffer).
// z < 8 : x[b=z][c][s] fp32 -> xt[b][s][c] bf16          (grid x:32, y:16)
// z >= 8: W[c][e] fp32 (weight z-8) -> Wt[e][c] bf16     (grid x:16, y:16)
// ---------------------------------------------------------------------------
__global__ __launch_bounds__(256) void transpose_xw(
    const float* __restrict__ x, __bf16* __restrict__ xt,
    const float* __restrict__ w0, const float* __restrict__ w1,
    const float* __restrict__ w2, const float* __restrict__ w3,
    __bf16* __restrict__ d0, __bf16* __restrict__ d1,
    __bf16* __restrict__ d2, __bf16* __restrict__ d3,
    float* __restrict__ stats)
{
    __shared__ float T[32][33];
    const int r8 = threadIdx.x >> 5, c32 = threadIdx.x & 31;
    const int z = blockIdx.z;
    if (z < 8) {
        const int b = z, c0 = blockIdx.y * 32, s0 = blockIdx.x * 32;
#pragma unroll
        for (int i = 0; i < 4; i++)
            T[r8 + i * 8][c32] =
                x[((size_t)b * Cc + c0 + r8 + i * 8) * Ss + s0 + c32];
        __syncthreads();
#pragma unroll
        for (int i = 0; i < 4; i++)
            xt[((size_t)b * Ss + s0 + r8 + i * 8) * Cc + c0 + c32] =
                cvt_bf16(T[c32][r8 + i * 8]);
    } else {
        if (z == 8 && blockIdx.x == 0 && blockIdx.y == 0) {
            stats[threadIdx.x] = 0.0f;            // 512 floats: B*G*2
            stats[threadIdx.x + 256] = 0.0f;
        }
        if (blockIdx.x >= 16) return;
        const int m = z - 8;
        const float* src = (m == 0) ? w0 : (m == 1) ? w1 : (m == 2) ? w2 : w3;
        __bf16* dst = (m == 0) ? d0 : (m == 1) ? d1 : (m == 2) ? d2 : d3;
        const int e0 = blockIdx.x * 32, c0 = blockIdx.y * 32;
#pragma unroll
        for (int i = 0; i < 4; i++)
            T[r8 + i * 8][c32] = src[(size_t)(c0 + r8 + i * 8) * Ee + e0 + c32];
        __syncthreads();
#pragma unroll
        for (int i = 0; i < 4; i++)
            dst[(size_t)(e0 + r8 + i * 8) * Cc + c0 + c32] =
                cvt_bf16(T[c32][r8 + i * 8]);
    }
}

// ---------------------------------------------------------------------------
// K1: fused QKV MFMA GEMM.  out[s][e] = xt[s][:] . Wt[e][:] + bias[e]
// Q,K -> [b][h][s][d] bf16;  V -> vt[b][h][d][S] via LDS-transpose epilogue.
// LDS union: T (34 KB, epilogue-only) overlaps As+Bs (16 KB, K-loop-only).
// ---------------------------------------------------------------------------
__global__ __launch_bounds__(256) void qkv_mfma(
    const __bf16* __restrict__ xt,
    const __bf16* __restrict__ wqt, const __bf16* __restrict__ wkt,
    const __bf16* __restrict__ wvt,
    const float* __restrict__ bq, const float* __restrict__ bk,
    const float* __restrict__ bv,
    __bf16* __restrict__ qb, __bf16* __restrict__ kb, __bf16* __restrict__ vt)
{
    const int b = blockIdx.z;
    const int wsel = blockIdx.y >> 2;
    const int e0 = (blockIdx.y & 3) * 128;
    const int s0 = blockIdx.x * 128;
    const __bf16* A  = xt + (size_t)b * Ss * Cc;
    const __bf16* Bm = (wsel == 0) ? wqt : (wsel == 1) ? wkt : wvt;
    const float*  bias = (wsel == 0) ? bq : (wsel == 1) ? bk : bv;

    __shared__ __align__(16) char smem[128 * 136 * 2];   // 34816 B
    __bf16* As = (__bf16*)smem;                 // 128*32
    __bf16* Bs = (__bf16*)(smem + 8192);        // 128*32
    __bf16* T  = (__bf16*)smem;                 // 128*136 (epilogue)

    const int wave = threadIdx.x >> 6, lane = threadIdx.x & 63;
    const int lid = lane & 15, quad = lane >> 4;
    const int wm = wave & 1, wn = wave >> 1;
    const int srow = lane >> 2, sch = lane & 3;   // staging: 16 rows x 4 chunks

    f32x4 acc[4][4] = {};

    for (int k0 = 0; k0 < Cc; k0 += 32) {
#pragma unroll
        for (int i = 0; i < 2; i++) {
            const int inst = wave * 2 + i;        // 0..7, 16 rows each
            const int r = inst * 16 + srow;
            gld16(&A [(size_t)(s0 + r) * Cc + k0 + sch * 8], &As[inst * 512]);
            gld16(&Bm[(size_t)(e0 + r) * Cc + k0 + sch * 8], &Bs[inst * 512]);
        }
        __syncthreads();
        bf16x8 af[4], bf[4];
#pragma unroll
        for (int i = 0; i < 4; i++)
            af[i] = *(const bf16x8*)&As[(wm * 64 + i * 16 + lid) * 32 + quad * 8];
#pragma unroll
        for (int j = 0; j < 4; j++)
            bf[j] = *(const bf16x8*)&Bs[(wn * 64 + j * 16 + lid) * 32 + quad * 8];
#pragma unroll
        for (int i = 0; i < 4; i++)
#pragma unroll
            for (int j = 0; j < 4; j++)
                acc[i][j] = __builtin_amdgcn_mfma_f32_16x16x32_bf16(
                    af[i], bf[j], acc[i][j], 0, 0, 0);
        __syncthreads();
    }

    float bj[4];
#pragma unroll
    for (int j = 0; j < 4; j++) bj[j] = bias[e0 + wn * 64 + j * 16 + lid];

    if (wsel == 2) {
        // V: transpose through LDS, emit vt[b][h][d][S] with 16B stores
#pragma unroll
        for (int i = 0; i < 4; i++) {
            const int s4 = wm * 64 + i * 16 + quad * 4;
#pragma unroll
            for (int j = 0; j < 4; j++) {
                const int e_l = wn * 64 + j * 16 + lid;
                unsigned short u0 = __builtin_bit_cast(unsigned short, cvt_bf16(acc[i][j][0] + bj[j]));
                unsigned short u1 = __builtin_bit_cast(unsigned short, cvt_bf16(acc[i][j][1] + bj[j]));
                unsigned short u2 = __builtin_bit_cast(unsigned short, cvt_bf16(acc[i][j][2] + bj[j]));
                unsigned short u3 = __builtin_bit_cast(unsigned short, cvt_bf16(acc[i][j][3] + bj[j]));
                uint2 pk;
                pk.x = (unsigned)u0 | ((unsigned)u1 << 16);
                pk.y = (unsigned)u2 | ((unsigned)u3 << 16);
                *(uint2*)&T[e_l * 136 + s4] = pk;
            }
        }
        __syncthreads();
        const int t = threadIdx.x;
#pragma unroll
        for (int it = 0; it < 8; it++) {
            const int idx = t + it * 256;
            const int e_l = idx >> 4, c8 = (idx & 15) * 8;
            bf16x8 val = *(const bf16x8*)&T[e_l * 136 + c8];
            const int e_g = e0 + e_l;
            const int head = e_g >> 6, d = e_g & 63;
            *(bf16x8*)&vt[(((size_t)b * nHd + head) * Hd + d) * Ss + s0 + c8] = val;
        }
    } else {
        __bf16* outp = (wsel == 0) ? qb : kb;
#pragma unroll
        for (int i = 0; i < 4; i++) {
#pragma unroll
            for (int j = 0; j < 4; j++) {
                const int e1 = e0 + wn * 64 + j * 16 + lid;
                const int head = e1 >> 6, d = e1 & 63;
#pragma unroll
                for (int r = 0; r < 4; r++) {
                    const int s1 = s0 + wm * 64 + i * 16 + quad * 4 + r;
                    outp[(((size_t)b * nHd + head) * Ss + s1) * Hd + d] =
                        cvt_bf16(acc[i][j][r] + bj[j]);
                }
            }
        }
    }
}

// ---------------------------------------------------------------------------
// K2: MFMA flash attention, S^T orientation, no-max softmax, 128-key tiles.
// P never touches LDS: C-layout -> A-layout via one cross-half register
// exchange (__shfl_xor 32). LDS = Ks 16KB + Vs 16KB only.
// ---------------------------------------------------------------------------
__global__ __launch_bounds__(256, 2) void attn_mfma(
    const __bf16* __restrict__ q, const __bf16* __restrict__ k,
    const __bf16* __restrict__ vt, __bf16* __restrict__ attn_out)
{
    const int bh = blockIdx.x;          // bh-major: q-tiles of one bh -> one XCD
    const int s0 = blockIdx.y * 128;
    const __bf16* qp = q  + (size_t)bh * Ss * Hd;
    const __bf16* kp = k  + (size_t)bh * Ss * Hd;
    const __bf16* vp = vt + (size_t)bh * Hd * Ss;

    __shared__ __align__(16) __bf16 Ks[128 * 64];     // [sk][d], chunk-swizzled
    __shared__ __align__(16) __bf16 Vs[64 * 128];     // [d][sk], chunk-swizzled

    const int wave = threadIdx.x >> 6, lane = threadIdx.x & 63;
    const int nl = lane & 31, h = lane >> 5;

    const int sq = s0 + wave * 32 + nl;
    bf16x8 qf[4];
#pragma unroll
    for (int kk2 = 0; kk2 < 4; kk2++)
        qf[kk2] = *(const bf16x8*)&qp[(size_t)sq * Hd + kk2 * 16 + h * 8];

    f32x16 oacc[2] = {};
    float rs = 0.0f;
    const float cexp = 0.125f * 1.44269504f;   // scale * log2(e)

    const int srow8 = lane >> 3, sch8 = lane & 7;     // K staging
    const int srow4 = lane >> 4, sch16 = lane & 15;   // V staging

    for (int kt = 0; kt < 8; kt++) {
#pragma unroll
        for (int i = 0; i < 4; i++) {
            const int inst = wave * 4 + i;            // 0..15
            const int rK = inst * 8 + srow8;          // K: 8 rows/inst
            gld16(&kp[(size_t)(kt * 128 + rK) * Hd + ((sch8 ^ (rK & 7)) * 8)],
                  &Ks[inst * 512]);
            const int dR = inst * 4 + srow4;          // V: 4 rows/inst
            gld16(&vp[(size_t)dR * Ss + kt * 128 + ((sch16 ^ (dR & 15)) * 8)],
                  &Vs[inst * 512]);                   // 512 el = 1024 B/inst
        }
        __syncthreads();

        // scores: S^T[sk][sq], 4 sk-tiles of 32, K-dim = d (4 steps of 16)
        f32x16 sc[4] = {};
#pragma unroll
        for (int kk2 = 0; kk2 < 4; kk2++) {
#pragma unroll
            for (int mt = 0; mt < 4; mt++) {
                bf16x8 kf = *(const bf16x8*)&Ks[(mt * 32 + nl) * 64 +
                                                (((2 * kk2 + h) ^ (nl & 7)) * 8)];
                sc[mt] = __builtin_amdgcn_mfma_f32_32x32x16_bf16(
                    kf, qf[kk2], sc[mt], 0, 0, 0);
            }
        }

        // no-max softmax + in-register C->A relayout.
        // Lane (nl,h) owns q-group Gq = P[sq=nl][sk: mt*32 + 8q + 4h + 0..3].
        // A-frag (kk=2mt+g) needs sk = mt*32 + g*16 + h*8 + 0..7:
        //   h0 keeps q0,q2, swaps out q1,q3 for partner's q0,q2 (and v.v.).
        unsigned frag[8][4];
#pragma unroll
        for (int mt = 0; mt < 4; mt++) {
            float p[16];
#pragma unroll
            for (int r = 0; r < 16; r++) {
                p[r] = __builtin_amdgcn_exp2f(sc[mt][r] * cexp);
                rs += p[r];
            }
            unsigned G[4][2];
#pragma unroll
            for (int qg = 0; qg < 4; qg++) {
                G[qg][0] = pk_bf16_rtz(p[4 * qg + 1], p[4 * qg + 0]);
                G[qg][1] = pk_bf16_rtz(p[4 * qg + 3], p[4 * qg + 2]);
            }
            const unsigned sA0 = h ? G[0][0] : G[1][0];
            const unsigned sA1 = h ? G[0][1] : G[1][1];
            const unsigned sB0 = h ? G[2][0] : G[3][0];
            const unsigned sB1 = h ? G[2][1] : G[3][1];
            const unsigned rA0 = __shfl_xor(sA0, 32, 64);
            const unsigned rA1 = __shfl_xor(sA1, 32, 64);
            const unsigned rB0 = __shfl_xor(sB0, 32, 64);
            const unsigned rB1 = __shfl_xor(sB1, 32, 64);
            frag[2 * mt][0]     = h ? rA0     : G[0][0];
            frag[2 * mt][1]     = h ? rA1     : G[0][1];
            frag[2 * mt][2]     = h ? G[1][0] : rA0;
            frag[2 * mt][3]     = h ? G[1][1] : rA1;
            frag[2 * mt + 1][0] = h ? rB0     : G[2][0];
            frag[2 * mt + 1][1] = h ? rB1     : G[2][1];
            frag[2 * mt + 1][2] = h ? G[3][0] : rB0;
            frag[2 * mt + 1][3] = h ? G[3][1] : rB1;
        }

        // PV: O[sq][d] = P[sq][sk] . V[sk][d]
#pragma unroll
        for (int kk = 0; kk < 8; kk++) {
            u32x4 fv = {frag[kk][0], frag[kk][1], frag[kk][2], frag[kk][3]};
            bf16x8 pf = __builtin_bit_cast(bf16x8, fv);
#pragma unroll
            for (int dt = 0; dt < 2; dt++) {
                bf16x8 vf = *(const bf16x8*)&Vs[(dt * 32 + nl) * 128 +
                                                (((kk * 2 + h) ^ (nl & 15)) * 8)];
                oacc[dt] = __builtin_amdgcn_mfma_f32_32x32x16_bf16(
                    pf, vf, oacc[dt], 0, 0, 0);
            }
        }
        __syncthreads();
    }

    // epilogue: l = cross-half sum of rs; normalize; store [b][s][e]
    rs += __shfl_xor(rs, 32, 64);
    const float inv = 1.0f / rs;
    const int b = bh >> 3, head = bh & 7;
#pragma unroll
    for (int r = 0; r < 16; r++) {
        const int rowq = (r & 3) + 8 * (r >> 2) + 4 * h;
        const float invr = __shfl(inv, rowq, 64);
        const int s1 = s0 + wave * 32 + rowq;
#pragma unroll
        for (int dt = 0; dt < 2; dt++)
            attn_out[((size_t)b * Ss + s1) * Ee + head * Hd + dt * 32 + nl] =
                cvt_bf16(oacc[dt][r] * invr);
    }
}

// ---------------------------------------------------------------------------
// K3: output projection, M=eo N=s; y[b][eo][s] bf16 (+bias+residual).
// Also accumulates GroupNorm partial sums (per-wave reduce + atomics).
// ---------------------------------------------------------------------------
__global__ __launch_bounds__(256) void outproj_mfma(
    const __bf16* __restrict__ attnb, const __bf16* __restrict__ wot,
    const float* __restrict__ bo, const float* __restrict__ xin,
    __bf16* __restrict__ y, float* __restrict__ stats)
{
    const int b  = blockIdx.z;
    const int e0 = blockIdx.y * 128;   // eo
    const int s0 = blockIdx.x * 128;
    const __bf16* Bm = attnb + (size_t)b * Ss * Ee;   // [s][ei]

    __shared__ __align__(16) __bf16 As[128 * 32];
    __shared__ __align__(16) __bf16 Bs[128 * 32];

    const int wave = threadIdx.x >> 6, lane = threadIdx.x & 63;
    const int lid = lane & 15, quad = lane >> 4;
    const int wm = wave & 1, wn = wave >> 1;
    const int srow = lane >> 2, sch = lane & 3;

    f32x4 acc[4][4] = {};

    for (int k0 = 0; k0 < Ee; k0 += 32) {
#pragma unroll
        for (int i = 0; i < 2; i++) {
            const int inst = wave * 2 + i;
            const int r = inst * 16 + srow;
            gld16(&wot[(size_t)(e0 + r) * Ee + k0 + sch * 8], &As[inst * 512]);
            gld16(&Bm [(size_t)(s0 + r) * Ee + k0 + sch * 8], &Bs[inst * 512]);
        }
        __syncthreads();
        bf16x8 af[4], bf[4];
#pragma unroll
        for (int i = 0; i < 4; i++)
            af[i] = *(const bf16x8*)&As[(wm * 64 + i * 16 + lid) * 32 + quad * 8];
#pragma unroll
        for (int j = 0; j < 4; j++)
            bf[j] = *(const bf16x8*)&Bs[(wn * 64 + j * 16 + lid) * 32 + quad * 8];
#pragma unroll
        for (int i = 0; i < 4; i++)
#pragma unroll
            for (int j = 0; j < 4; j++)
                acc[i][j] = __builtin_amdgcn_mfma_f32_16x16x32_bf16(
                    af[i], bf[j], acc[i][j], 0, 0, 0);
        __syncthreads();
    }

    float gs[4] = {}, gs2[4] = {};
#pragma unroll
    for (int i = 0; i < 4; i++) {
#pragma unroll
        for (int r = 0; r < 4; r++) {
            const int eo1 = e0 + wm * 64 + i * 16 + quad * 4 + r;
            const float bb = bo[eo1];
#pragma unroll
            for (int j = 0; j < 4; j++) {
                const int s1 = s0 + wn * 64 + j * 16 + lid;
                const size_t idx = ((size_t)b * Ee + eo1) * Ss + s1;
                const float v = acc[i][j][r] + bb + xin[idx];
                y[idx] = cvt_bf16(v);
                gs[i]  += v;
                gs2[i] += v * v;
            }
        }
    }
    // per-wave reduce (all lanes of a wave share wm -> same 4 groups)
#pragma unroll
    for (int i = 0; i < 4; i++) {
        float a = gs[i], c = gs2[i];
#pragma unroll
        for (int off = 32; off > 0; off >>= 1) {
            a += __shfl_down(a, off, 64);
            c += __shfl_down(c, off, 64);
        }
        if (lane == 0) {
            const int g = (e0 >> 4) + wm * 4 + i;           // 0..31
            atomicAdd(&stats[(b * Gg + g) * 2 + 0], a);
            atomicAdd(&stats[(b * Gg + g) * 2 + 1], c);
        }
    }
}

// ---------------------------------------------------------------------------
// K4: GroupNorm, single pass (stats precomputed).  y bf16 [B][E][S]; out fp32.
// ---------------------------------------------------------------------------
__global__ __launch_bounds__(256) void gnorm_kernel(
    const __bf16* __restrict__ y, const float* __restrict__ gamma,
    const float* __restrict__ beta, const float* __restrict__ stats,
    float* __restrict__ out)
{
    const int bg = blockIdx.x;
    const int b = bg >> 5, g = bg & 31;
    const size_t base = ((size_t)b * Ee + g * Cpg) * Ss;
    const bf16x8* y8 = (const bf16x8*)(y + base);
    constexpr int N8 = (Cpg * Ss) / 8;   // 2048
    constexpr float Nf = (float)(Cpg * Ss);

    const float mean = stats[bg * 2 + 0] / Nf;
    const float var  = stats[bg * 2 + 1] / Nf - mean * mean;
    const float rstd = rsqrtf(var + 1e-5f);

    for (int i = threadIdx.x; i < N8; i += 256) {
        bf16x8 vv = y8[i];
        const int c = g * Cpg + (i >> 7);   // 128 bf16x8 per channel
        const float gm = gamma[c] * rstd;
        const float bt = beta[c];
        f32x4 r0, r1;
#pragma unroll
        for (int j = 0; j < 4; j++) r0[j] = ((float)vv[j] - mean) * gm + bt;
#pragma unroll
        for (int j = 0; j < 4; j++) r1[j] = ((float)vv[4 + j] - mean) * gm + bt;
        *(f32x4*)&out[base + (size_t)i * 8]     = r0;
        *(f32x4*)&out[base + (size_t)i * 8 + 4] = r1;
    }
}

// ---------------------------------------------------------------------------
extern "C" void kernel_launch(void* const* d_in, const int* in_sizes, int n_in,
                              void* d_out, int out_size, void* d_ws, size_t ws_size,
                              hipStream_t stream)
{
    const float* x     = (const float*)d_in[0];
    const float* Wq    = (const float*)d_in[1];
    const float* bq    = (const float*)d_in[2];
    const float* Wk    = (const float*)d_in[3];
    const float* bk    = (const float*)d_in[4];
    const float* Wv    = (const float*)d_in[5];
    const float* bv    = (const float*)d_in[6];
    const float* Wo    = (const float*)d_in[7];
    const float* bo    = (const float*)d_in[8];
    const float* gamma = (const float*)d_in[9];
    const float* beta  = (const float*)d_in[10];
    float* out = (float*)d_out;

    // workspace layout (bytes)
    char* ws = (char*)d_ws;
    __bf16* xt    = (__bf16*)ws;                          //  8 MiB
    __bf16* wqt   = (__bf16*)(ws + (8u << 20));           // 512 KiB
    __bf16* wkt   = (__bf16*)(ws + (8u << 20) + (512u << 10));
    __bf16* wvt   = (__bf16*)(ws + (9u << 20));
    __bf16* wot   = (__bf16*)(ws + (9u << 20) + (512u << 10));
    __bf16* qb    = (__bf16*)(ws + (10u << 20));          //  8 MiB
    __bf16* kb    = (__bf16*)(ws + (18u << 20));          //  8 MiB
    __bf16* vtb   = (__bf16*)(ws + (26u << 20));          //  8 MiB (V^T)
    __bf16* attnb = (__bf16*)(ws + (34u << 20));          //  8 MiB
    __bf16* yb    = (__bf16*)(ws + (42u << 20));          //  8 MiB
    float*  statb = (float*) (ws + (50u << 20));          //  2 KiB (B*G*2)

    transpose_xw<<<dim3(32, 16, 12), 256, 0, stream>>>(
        x, xt, Wq, Wk, Wv, Wo, wqt, wkt, wvt, wot, statb);

    qkv_mfma<<<dim3(Ss / 128, 12, Bn), 256, 0, stream>>>(
        xt, wqt, wkt, wvt, bq, bk, bv, qb, kb, vtb);

    attn_mfma<<<dim3(Bn * nHd, Ss / 128), 256, 0, stream>>>(qb, kb, vtb, attnb);

    outproj_mfma<<<dim3(Ss / 128, Ee / 128, Bn), 256, 0, stream>>>(
        attnb, wot, bo, x, yb, statb);

    gnorm_kernel<<<Bn * Gg, 256, 0, stream>>>(yb, gamma, beta, statb, out);
}

// Round 7
// 155.387 us; speedup vs baseline: 1.0564x; 1.0564x over previous
//
#include <hip/hip_runtime.h>
#include <math.h>

constexpr int Bn  = 8;
constexpr int Cc  = 512;
constexpr int Ss  = 1024;   // H*W
constexpr int Ee  = 512;
constexpr int nHd = 8;
constexpr int Hd  = 64;
constexpr int Gg  = 32;
constexpr int Cpg = 16;

typedef __bf16 bf16x8 __attribute__((ext_vector_type(8)));
typedef float  f32x4  __attribute__((ext_vector_type(4)));
typedef float  f32x16 __attribute__((ext_vector_type(16)));
typedef unsigned u32x4 __attribute__((ext_vector_type(4)));

__device__ inline __bf16 cvt_bf16(float f) {
    unsigned u = __builtin_bit_cast(unsigned, f);
    u += 0x7fffu + ((u >> 16) & 1u);          // RTNE (finite values)
    unsigned short h = (unsigned short)(u >> 16);
    return __builtin_bit_cast(__bf16, h);
}

__device__ inline void gld16(const __bf16* g, __bf16* l) {
    __builtin_amdgcn_global_load_lds(
        (const __attribute__((address_space(1))) void*)g,
        (__attribute__((address_space(3))) void*)l, 16, 0, 0);
}

// pack two fp32 -> 2 bf16 (RTZ) in one dword: low = lo, high = hi
__device__ inline unsigned pk_bf16_rtz(float hi, float lo) {
    return __builtin_amdgcn_perm(__builtin_bit_cast(unsigned, hi),
                                 __builtin_bit_cast(unsigned, lo), 0x07060302u);
}

// ---------------------------------------------------------------------------
// Pre-pass: fused transposes (+ zero the GroupNorm stats buffer).
// ---------------------------------------------------------------------------
__global__ __launch_bounds__(256) void transpose_xw(
    const float* __restrict__ x, __bf16* __restrict__ xt,
    const float* __restrict__ w0, const float* __restrict__ w1,
    const float* __restrict__ w2, const float* __restrict__ w3,
    __bf16* __restrict__ d0, __bf16* __restrict__ d1,
    __bf16* __restrict__ d2, __bf16* __restrict__ d3,
    float* __restrict__ stats)
{
    __shared__ float T[32][33];
    const int r8 = threadIdx.x >> 5, c32 = threadIdx.x & 31;
    const int z = blockIdx.z;
    if (z < 8) {
        const int b = z, c0 = blockIdx.y * 32, s0 = blockIdx.x * 32;
#pragma unroll
        for (int i = 0; i < 4; i++)
            T[r8 + i * 8][c32] =
                x[((size_t)b * Cc + c0 + r8 + i * 8) * Ss + s0 + c32];
        __syncthreads();
#pragma unroll
        for (int i = 0; i < 4; i++)
            xt[((size_t)b * Ss + s0 + r8 + i * 8) * Cc + c0 + c32] =
                cvt_bf16(T[c32][r8 + i * 8]);
    } else {
        if (z == 8 && blockIdx.x == 0 && blockIdx.y == 0) {
            stats[threadIdx.x] = 0.0f;            // 512 floats: B*G*2
            stats[threadIdx.x + 256] = 0.0f;
        }
        if (blockIdx.x >= 16) return;
        const int m = z - 8;
        const float* src = (m == 0) ? w0 : (m == 1) ? w1 : (m == 2) ? w2 : w3;
        __bf16* dst = (m == 0) ? d0 : (m == 1) ? d1 : (m == 2) ? d2 : d3;
        const int e0 = blockIdx.x * 32, c0 = blockIdx.y * 32;
#pragma unroll
        for (int i = 0; i < 4; i++)
            T[r8 + i * 8][c32] = src[(size_t)(c0 + r8 + i * 8) * Ee + e0 + c32];
        __syncthreads();
#pragma unroll
        for (int i = 0; i < 4; i++)
            dst[(size_t)(e0 + r8 + i * 8) * Cc + c0 + c32] =
                cvt_bf16(T[c32][r8 + i * 8]);
    }
}

// ---------------------------------------------------------------------------
// K1: fused QKV MFMA GEMM, double-buffered K-loop.
// Q,K -> [b][h][s][d] bf16;  V -> vt[b][h][d][S] via LDS-transpose epilogue.
// LDS: dbuf As/Bs 32 KB, unioned with epilogue T (34 KB) -> 34 KB.
// ---------------------------------------------------------------------------
__global__ __launch_bounds__(256) void qkv_mfma(
    const __bf16* __restrict__ xt,
    const __bf16* __restrict__ wqt, const __bf16* __restrict__ wkt,
    const __bf16* __restrict__ wvt,
    const float* __restrict__ bq, const float* __restrict__ bk,
    const float* __restrict__ bv,
    __bf16* __restrict__ qb, __bf16* __restrict__ kb, __bf16* __restrict__ vt)
{
    const int b = blockIdx.z;
    const int wsel = blockIdx.y >> 2;
    const int e0 = (blockIdx.y & 3) * 128;
    const int s0 = blockIdx.x * 128;
    const __bf16* A  = xt + (size_t)b * Ss * Cc;
    const __bf16* Bm = (wsel == 0) ? wqt : (wsel == 1) ? wkt : wvt;
    const float*  bias = (wsel == 0) ? bq : (wsel == 1) ? bk : bv;

    __shared__ __align__(16) char smem[128 * 136 * 2];   // 34816 B
    __bf16* T = (__bf16*)smem;                  // epilogue union

    const int wave = threadIdx.x >> 6, lane = threadIdx.x & 63;
    const int lid = lane & 15, quad = lane >> 4;
    const int wm = wave & 1, wn = wave >> 1;
    const int srow = lane >> 2, sch = lane & 3;

    f32x4 acc[4][4] = {};

    auto stage = [&](int k0, int bufi) {
        __bf16* Asb = (__bf16*)(smem + bufi * 16384);
        __bf16* Bsb = (__bf16*)(smem + bufi * 16384 + 8192);
#pragma unroll
        for (int i = 0; i < 2; i++) {
            const int inst = wave * 2 + i;        // 0..7, 16 rows each
            const int r = inst * 16 + srow;
            gld16(&A [(size_t)(s0 + r) * Cc + k0 + sch * 8], &Asb[inst * 512]);
            gld16(&Bm[(size_t)(e0 + r) * Cc + k0 + sch * 8], &Bsb[inst * 512]);
        }
    };

    stage(0, 0);
    for (int it = 0; it < 16; it++) {
        __syncthreads();                          // staging of buf it&1 done
        if (it + 1 < 16) stage((it + 1) * 32, (it + 1) & 1);
        const __bf16* Asb = (const __bf16*)(smem + (it & 1) * 16384);
        const __bf16* Bsb = Asb + 4096;
        bf16x8 af[4], bf[4];
#pragma unroll
        for (int i = 0; i < 4; i++)
            af[i] = *(const bf16x8*)&Asb[(wm * 64 + i * 16 + lid) * 32 + quad * 8];
#pragma unroll
        for (int j = 0; j < 4; j++)
            bf[j] = *(const bf16x8*)&Bsb[(wn * 64 + j * 16 + lid) * 32 + quad * 8];
#pragma unroll
        for (int i = 0; i < 4; i++)
#pragma unroll
            for (int j = 0; j < 4; j++)
                acc[i][j] = __builtin_amdgcn_mfma_f32_16x16x32_bf16(
                    af[i], bf[j], acc[i][j], 0, 0, 0);
    }
    __syncthreads();                              // LDS free for T

    float bj[4];
#pragma unroll
    for (int j = 0; j < 4; j++) bj[j] = bias[e0 + wn * 64 + j * 16 + lid];

    if (wsel == 2) {
#pragma unroll
        for (int i = 0; i < 4; i++) {
            const int s4 = wm * 64 + i * 16 + quad * 4;
#pragma unroll
            for (int j = 0; j < 4; j++) {
                const int e_l = wn * 64 + j * 16 + lid;
                unsigned short u0 = __builtin_bit_cast(unsigned short, cvt_bf16(acc[i][j][0] + bj[j]));
                unsigned short u1 = __builtin_bit_cast(unsigned short, cvt_bf16(acc[i][j][1] + bj[j]));
                unsigned short u2 = __builtin_bit_cast(unsigned short, cvt_bf16(acc[i][j][2] + bj[j]));
                unsigned short u3 = __builtin_bit_cast(unsigned short, cvt_bf16(acc[i][j][3] + bj[j]));
                uint2 pk;
                pk.x = (unsigned)u0 | ((unsigned)u1 << 16);
                pk.y = (unsigned)u2 | ((unsigned)u3 << 16);
                *(uint2*)&T[e_l * 136 + s4] = pk;
            }
        }
        __syncthreads();
        const int t = threadIdx.x;
#pragma unroll
        for (int it = 0; it < 8; it++) {
            const int idx = t + it * 256;
            const int e_l = idx >> 4, c8 = (idx & 15) * 8;
            bf16x8 val = *(const bf16x8*)&T[e_l * 136 + c8];
            const int e_g = e0 + e_l;
            const int head = e_g >> 6, d = e_g & 63;
            *(bf16x8*)&vt[(((size_t)b * nHd + head) * Hd + d) * Ss + s0 + c8] = val;
        }
    } else {
        __bf16* outp = (wsel == 0) ? qb : kb;
#pragma unroll
        for (int i = 0; i < 4; i++) {
#pragma unroll
            for (int j = 0; j < 4; j++) {
                const int e1 = e0 + wn * 64 + j * 16 + lid;
                const int head = e1 >> 6, d = e1 & 63;
#pragma unroll
                for (int r = 0; r < 4; r++) {
                    const int s1 = s0 + wm * 64 + i * 16 + quad * 4 + r;
                    outp[(((size_t)b * nHd + head) * Ss + s1) * Hd + d] =
                        cvt_bf16(acc[i][j][r] + bj[j]);
                }
            }
        }
    }
}

// ---------------------------------------------------------------------------
// K2: MFMA flash attention, S^T orientation, no-max softmax, 128-key tiles,
// double-buffered K/V staging (LDS 64 KB), register-only P relayout.
// ---------------------------------------------------------------------------
__global__ __launch_bounds__(256, 2) void attn_mfma(
    const __bf16* __restrict__ q, const __bf16* __restrict__ k,
    const __bf16* __restrict__ vt, __bf16* __restrict__ attn_out)
{
    const int bh = blockIdx.x;
    const int s0 = blockIdx.y * 128;
    const __bf16* qp = q  + (size_t)bh * Ss * Hd;
    const __bf16* kp = k  + (size_t)bh * Ss * Hd;
    const __bf16* vp = vt + (size_t)bh * Hd * Ss;

    __shared__ __align__(16) __bf16 Ks[2][128 * 64];   // [sk][d], swizzled
    __shared__ __align__(16) __bf16 Vs[2][64 * 128];   // [d][sk], swizzled

    const int wave = threadIdx.x >> 6, lane = threadIdx.x & 63;
    const int nl = lane & 31, h = lane >> 5;

    const int sq = s0 + wave * 32 + nl;
    bf16x8 qf[4];
#pragma unroll
    for (int kk2 = 0; kk2 < 4; kk2++)
        qf[kk2] = *(const bf16x8*)&qp[(size_t)sq * Hd + kk2 * 16 + h * 8];

    f32x16 oacc[2] = {};
    float rs = 0.0f;
    const float cexp = 0.125f * 1.44269504f;   // scale * log2(e)

    const int srow8 = lane >> 3, sch8 = lane & 7;     // K staging
    const int srow4 = lane >> 4, sch16 = lane & 15;   // V staging

    auto stageKV = [&](int kt, int bufi) {
        __bf16* Ksb = Ks[bufi];
        __bf16* Vsb = Vs[bufi];
#pragma unroll
        for (int i = 0; i < 4; i++) {
            const int inst = wave * 4 + i;            // 0..15
            const int rK = inst * 8 + srow8;
            gld16(&kp[(size_t)(kt * 128 + rK) * Hd + ((sch8 ^ (rK & 7)) * 8)],
                  &Ksb[inst * 512]);
            const int dR = inst * 4 + srow4;
            gld16(&vp[(size_t)dR * Ss + kt * 128 + ((sch16 ^ (dR & 15)) * 8)],
                  &Vsb[inst * 512]);
        }
    };

    stageKV(0, 0);
    for (int kt = 0; kt < 8; kt++) {
        __syncthreads();                               // buf kt&1 staged
        if (kt + 1 < 8) stageKV(kt + 1, (kt + 1) & 1);
        const __bf16* Ksb = Ks[kt & 1];
        const __bf16* Vsb = Vs[kt & 1];

        // scores: S^T[sk][sq], 4 sk-tiles of 32, K-dim = d (4 steps of 16)
        f32x16 sc[4] = {};
#pragma unroll
        for (int kk2 = 0; kk2 < 4; kk2++) {
#pragma unroll
            for (int mt = 0; mt < 4; mt++) {
                bf16x8 kf = *(const bf16x8*)&Ksb[(mt * 32 + nl) * 64 +
                                                 (((2 * kk2 + h) ^ (nl & 7)) * 8)];
                sc[mt] = __builtin_amdgcn_mfma_f32_32x32x16_bf16(
                    kf, qf[kk2], sc[mt], 0, 0, 0);
            }
        }

        // no-max softmax + in-register C->A relayout (cross-half shfl).
        unsigned frag[8][4];
#pragma unroll
        for (int mt = 0; mt < 4; mt++) {
            float p[16];
#pragma unroll
            for (int r = 0; r < 16; r++) {
                p[r] = __builtin_amdgcn_exp2f(sc[mt][r] * cexp);
                rs += p[r];
            }
            unsigned G[4][2];
#pragma unroll
            for (int qg = 0; qg < 4; qg++) {
                G[qg][0] = pk_bf16_rtz(p[4 * qg + 1], p[4 * qg + 0]);
                G[qg][1] = pk_bf16_rtz(p[4 * qg + 3], p[4 * qg + 2]);
            }
            const unsigned sA0 = h ? G[0][0] : G[1][0];
            const unsigned sA1 = h ? G[0][1] : G[1][1];
            const unsigned sB0 = h ? G[2][0] : G[3][0];
            const unsigned sB1 = h ? G[2][1] : G[3][1];
            const unsigned rA0 = __shfl_xor(sA0, 32, 64);
            const unsigned rA1 = __shfl_xor(sA1, 32, 64);
            const unsigned rB0 = __shfl_xor(sB0, 32, 64);
            const unsigned rB1 = __shfl_xor(sB1, 32, 64);
            frag[2 * mt][0]     = h ? rA0     : G[0][0];
            frag[2 * mt][1]     = h ? rA1     : G[0][1];
            frag[2 * mt][2]     = h ? G[1][0] : rA0;
            frag[2 * mt][3]     = h ? G[1][1] : rA1;
            frag[2 * mt + 1][0] = h ? rB0     : G[2][0];
            frag[2 * mt + 1][1] = h ? rB1     : G[2][1];
            frag[2 * mt + 1][2] = h ? G[3][0] : rB0;
            frag[2 * mt + 1][3] = h ? G[3][1] : rB1;
        }

        // PV: O[sq][d] = P[sq][sk] . V[sk][d]
#pragma unroll
        for (int kk = 0; kk < 8; kk++) {
            u32x4 fv = {frag[kk][0], frag[kk][1], frag[kk][2], frag[kk][3]};
            bf16x8 pf = __builtin_bit_cast(bf16x8, fv);
#pragma unroll
            for (int dt = 0; dt < 2; dt++) {
                bf16x8 vf = *(const bf16x8*)&Vsb[(dt * 32 + nl) * 128 +
                                                 (((kk * 2 + h) ^ (nl & 15)) * 8)];
                oacc[dt] = __builtin_amdgcn_mfma_f32_32x32x16_bf16(
                    pf, vf, oacc[dt], 0, 0, 0);
            }
        }
    }

    // epilogue: l = cross-half sum of rs; normalize; store [b][s][e]
    rs += __shfl_xor(rs, 32, 64);
    const float inv = 1.0f / rs;
    const int b = bh >> 3, head = bh & 7;
#pragma unroll
    for (int r = 0; r < 16; r++) {
        const int rowq = (r & 3) + 8 * (r >> 2) + 4 * h;
        const float invr = __shfl(inv, rowq, 64);
        const int s1 = s0 + wave * 32 + rowq;
#pragma unroll
        for (int dt = 0; dt < 2; dt++)
            attn_out[((size_t)b * Ss + s1) * Ee + head * Hd + dt * 32 + nl] =
                cvt_bf16(oacc[dt][r] * invr);
    }
}

// ---------------------------------------------------------------------------
// K3: output projection, double-buffered; y[b][eo][s] bf16 (+bias+residual).
// Also accumulates GroupNorm partial sums (per-wave reduce + atomics).
// ---------------------------------------------------------------------------
__global__ __launch_bounds__(256) void outproj_mfma(
    const __bf16* __restrict__ attnb, const __bf16* __restrict__ wot,
    const float* __restrict__ bo, const float* __restrict__ xin,
    __bf16* __restrict__ y, float* __restrict__ stats)
{
    const int b  = blockIdx.z;
    const int e0 = blockIdx.y * 128;   // eo
    const int s0 = blockIdx.x * 128;
    const __bf16* Bm = attnb + (size_t)b * Ss * Ee;   // [s][ei]

    __shared__ __align__(16) char smem[32768];        // dbuf As/Bs

    const int wave = threadIdx.x >> 6, lane = threadIdx.x & 63;
    const int lid = lane & 15, quad = lane >> 4;
    const int wm = wave & 1, wn = wave >> 1;
    const int srow = lane >> 2, sch = lane & 3;

    f32x4 acc[4][4] = {};

    auto stage = [&](int k0, int bufi) {
        __bf16* Asb = (__bf16*)(smem + bufi * 16384);
        __bf16* Bsb = (__bf16*)(smem + bufi * 16384 + 8192);
#pragma unroll
        for (int i = 0; i < 2; i++) {
            const int inst = wave * 2 + i;
            const int r = inst * 16 + srow;
            gld16(&wot[(size_t)(e0 + r) * Ee + k0 + sch * 8], &Asb[inst * 512]);
            gld16(&Bm [(size_t)(s0 + r) * Ee + k0 + sch * 8], &Bsb[inst * 512]);
        }
    };

    stage(0, 0);
    for (int it = 0; it < 16; it++) {
        __syncthreads();
        if (it + 1 < 16) stage((it + 1) * 32, (it + 1) & 1);
        const __bf16* Asb = (const __bf16*)(smem + (it & 1) * 16384);
        const __bf16* Bsb = Asb + 4096;
        bf16x8 af[4], bf[4];
#pragma unroll
        for (int i = 0; i < 4; i++)
            af[i] = *(const bf16x8*)&Asb[(wm * 64 + i * 16 + lid) * 32 + quad * 8];
#pragma unroll
        for (int j = 0; j < 4; j++)
            bf[j] = *(const bf16x8*)&Bsb[(wn * 64 + j * 16 + lid) * 32 + quad * 8];
#pragma unroll
        for (int i = 0; i < 4; i++)
#pragma unroll
            for (int j = 0; j < 4; j++)
                acc[i][j] = __builtin_amdgcn_mfma_f32_16x16x32_bf16(
                    af[i], bf[j], acc[i][j], 0, 0, 0);
    }

    float gs[4] = {}, gs2[4] = {};
#pragma unroll
    for (int i = 0; i < 4; i++) {
#pragma unroll
        for (int r = 0; r < 4; r++) {
            const int eo1 = e0 + wm * 64 + i * 16 + quad * 4 + r;
            const float bb = bo[eo1];
#pragma unroll
            for (int j = 0; j < 4; j++) {
                const int s1 = s0 + wn * 64 + j * 16 + lid;
                const size_t idx = ((size_t)b * Ee + eo1) * Ss + s1;
                const float v = acc[i][j][r] + bb + xin[idx];
                y[idx] = cvt_bf16(v);
                gs[i]  += v;
                gs2[i] += v * v;
            }
        }
    }
#pragma unroll
    for (int i = 0; i < 4; i++) {
        float a = gs[i], c = gs2[i];
#pragma unroll
        for (int off = 32; off > 0; off >>= 1) {
            a += __shfl_down(a, off, 64);
            c += __shfl_down(c, off, 64);
        }
        if (lane == 0) {
            const int g = (e0 >> 4) + wm * 4 + i;           // 0..31
            atomicAdd(&stats[(b * Gg + g) * 2 + 0], a);
            atomicAdd(&stats[(b * Gg + g) * 2 + 1], c);
        }
    }
}

// ---------------------------------------------------------------------------
// K4: GroupNorm, single pass (stats precomputed).  y bf16 [B][E][S]; out fp32.
// ---------------------------------------------------------------------------
__global__ __launch_bounds__(256) void gnorm_kernel(
    const __bf16* __restrict__ y, const float* __restrict__ gamma,
    const float* __restrict__ beta, const float* __restrict__ stats,
    float* __restrict__ out)
{
    const int bg = blockIdx.x;
    const int b = bg >> 5, g = bg & 31;
    const size_t base = ((size_t)b * Ee + g * Cpg) * Ss;
    const bf16x8* y8 = (const bf16x8*)(y + base);
    constexpr int N8 = (Cpg * Ss) / 8;   // 2048
    constexpr float Nf = (float)(Cpg * Ss);

    const float mean = stats[bg * 2 + 0] / Nf;
    const float var  = stats[bg * 2 + 1] / Nf - mean * mean;
    const float rstd = rsqrtf(var + 1e-5f);

    for (int i = threadIdx.x; i < N8; i += 256) {
        bf16x8 vv = y8[i];
        const int c = g * Cpg + (i >> 7);   // 128 bf16x8 per channel
        const float gm = gamma[c] * rstd;
        const float bt = beta[c];
        f32x4 r0, r1;
#pragma unroll
        for (int j = 0; j < 4; j++) r0[j] = ((float)vv[j] - mean) * gm + bt;
#pragma unroll
        for (int j = 0; j < 4; j++) r1[j] = ((float)vv[4 + j] - mean) * gm + bt;
        *(f32x4*)&out[base + (size_t)i * 8]     = r0;
        *(f32x4*)&out[base + (size_t)i * 8 + 4] = r1;
    }
}

// ---------------------------------------------------------------------------
extern "C" void kernel_launch(void* const* d_in, const int* in_sizes, int n_in,
                              void* d_out, int out_size, void* d_ws, size_t ws_size,
                              hipStream_t stream)
{
    const float* x     = (const float*)d_in[0];
    const float* Wq    = (const float*)d_in[1];
    const float* bq    = (const float*)d_in[2];
    const float* Wk    = (const float*)d_in[3];
    const float* bk    = (const float*)d_in[4];
    const float* Wv    = (const float*)d_in[5];
    const float* bv    = (const float*)d_in[6];
    const float* Wo    = (const float*)d_in[7];
    const float* bo    = (const float*)d_in[8];
    const float* gamma = (const float*)d_in[9];
    const float* beta  = (const float*)d_in[10];
    float* out = (float*)d_out;

    // workspace layout (bytes)
    char* ws = (char*)d_ws;
    __bf16* xt    = (__bf16*)ws;                          //  8 MiB
    __bf16* wqt   = (__bf16*)(ws + (8u << 20));           // 512 KiB
    __bf16* wkt   = (__bf16*)(ws + (8u << 20) + (512u << 10));
    __bf16* wvt   = (__bf16*)(ws + (9u << 20));
    __bf16* wot   = (__bf16*)(ws + (9u << 20) + (512u << 10));
    __bf16* qb    = (__bf16*)(ws + (10u << 20));          //  8 MiB
    __bf16* kb    = (__bf16*)(ws + (18u << 20));          //  8 MiB
    __bf16* vtb   = (__bf16*)(ws + (26u << 20));          //  8 MiB (V^T)
    __bf16* attnb = (__bf16*)(ws + (34u << 20));          //  8 MiB
    __bf16* yb    = (__bf16*)(ws + (42u << 20));          //  8 MiB
    float*  statb = (float*) (ws + (50u << 20));          //  2 KiB (B*G*2)

    transpose_xw<<<dim3(32, 16, 12), 256, 0, stream>>>(
        x, xt, Wq, Wk, Wv, Wo, wqt, wkt, wvt, wot, statb);

    qkv_mfma<<<dim3(Ss / 128, 12, Bn), 256, 0, stream>>>(
        xt, wqt, wkt, wvt, bq, bk, bv, qb, kb, vtb);

    attn_mfma<<<dim3(Bn * nHd, Ss / 128), 256, 0, stream>>>(qb, kb, vtb, attnb);

    outproj_mfma<<<dim3(Ss / 128, Ee / 128, Bn), 256, 0, stream>>>(
        attnb, wot, bo, x, yb, statb);

    gnorm_kernel<<<Bn * Gg, 256, 0, stream>>>(yb, gamma, beta, statb, out);
}